// Round 2
// baseline (6058.664 us; speedup 1.0000x reference)
//
#include <hip/hip_runtime.h>
#include <cstdint>

#define WK 4
#define NN 100000
#define NE 1600000
#define NF 128
#define WN (WK*NN)                    // 400000
#define TILE 512
#define TPW ((NN + TILE - 1)/TILE)    // 196 tiles per worker
#define BSH 6                         // 64 nodes per bucket
#define BC  (1<<BSH)
#define BKT ((NN + BC - 1)/BC)        // 1563 buckets per worker

// ---------------- degree counting ----------------
__global__ void deg_kernel(const int* __restrict__ src, const int* __restrict__ dst,
                           int* __restrict__ cnt_out, int* __restrict__ cnt_in) {
    int w = blockIdx.y;
    int i = blockIdx.x * blockDim.x + threadIdx.x;
    if (i >= NE) return;
    unsigned s = (unsigned)src[(size_t)w*NE + i];
    unsigned d = (unsigned)dst[(size_t)w*NE + i];
    if (s < NN) atomicAdd(&cnt_out[w*NN + (int)s], 1);
    if (d < NN) atomicAdd(&cnt_in [w*NN + (int)d], 1);
}

// ---------------- prefix scan (3 kernels) over cnt_in -> row_start ----------------
__global__ void scan1_kernel(const int* __restrict__ cnt_in, int* __restrict__ row_start,
                             int* __restrict__ partials) {
    __shared__ int sdata[TILE];
    int w = blockIdx.y, t = blockIdx.x, tid = threadIdx.x;
    int g = t*TILE + tid;
    int v = (g < NN) ? cnt_in[w*NN + g] : 0;
    sdata[tid] = v;
    __syncthreads();
    for (int off = 1; off < TILE; off <<= 1) {
        int tmp = (tid >= off) ? sdata[tid - off] : 0;
        __syncthreads();
        sdata[tid] += tmp;
        __syncthreads();
    }
    if (tid == TILE-1) partials[w*TPW + t] = sdata[TILE-1];
    if (g < NN) row_start[w*NN + g] = sdata[tid] - v;   // exclusive within tile
}

__global__ void scan2_kernel(int* __restrict__ partials) {
    __shared__ int sdata[256];
    int w = blockIdx.x, tid = threadIdx.x;
    int v = (tid < TPW) ? partials[w*TPW + tid] : 0;
    sdata[tid] = v;
    __syncthreads();
    for (int off = 1; off < 256; off <<= 1) {
        int tmp = (tid >= off) ? sdata[tid - off] : 0;
        __syncthreads();
        sdata[tid] += tmp;
        __syncthreads();
    }
    if (tid < TPW) partials[w*TPW + tid] = sdata[tid] - v;  // exclusive tile offsets
}

__global__ void scan3_kernel(int* __restrict__ row_start, const int* __restrict__ partials) {
    int w = blockIdx.y, t = blockIdx.x, tid = threadIdx.x;
    int g = t*TILE + tid;
    if (g >= NN) return;
    row_start[w*NN + g] += partials[w*TPW + t];
}

// ---------------- counts -> rsqrt(max(deg,1)) into SEPARATE float arrays ----------------
__global__ void finalize_kernel(const int* __restrict__ cnt_out, const int* __restrict__ cnt_in,
                                float* __restrict__ inv_out, float* __restrict__ inv_in) {
    int i = blockIdx.x * blockDim.x + threadIdx.x;
    if (i >= WN) return;
    inv_out[i] = rsqrtf(fmaxf((float)cnt_out[i], 1.0f));
    inv_in [i] = rsqrtf(fmaxf((float)cnt_in [i], 1.0f));
}

// ---------------- bucket cursors: bcur[w][b] = row_start[w, b*BC] ----------------
__global__ void bucket_init_kernel(const int* __restrict__ row_start, int* __restrict__ bcur) {
    int i = blockIdx.x * blockDim.x + threadIdx.x;
    if (i >= WK*BKT) return;
    int w = i / BKT, b = i % BKT;
    bcur[i] = row_start[w*NN + (b<<BSH)];
}

// ---------------- bin edges by dst-bucket: binned[pos] = (d_local<<17)|src ----------------
// Append streams target only WK*BKT (~6K) cursors -> active-line window ~400KB,
// L2-resident -> near-1x write amplification (vs ~18x for per-node scatter).
__global__ void bin_kernel(const int* __restrict__ src, const int* __restrict__ dst,
                           int* __restrict__ bcur, int* __restrict__ binned) {
    int w = blockIdx.y;
    int i = blockIdx.x * blockDim.x + threadIdx.x;
    if (i >= NE) return;
    unsigned s = (unsigned)src[(size_t)w*NE + i];
    unsigned d = (unsigned)dst[(size_t)w*NE + i];
    if (s >= NN || d >= NN) return;                       // never index from garbage
    int b  = (int)(d >> BSH);
    int dl = (int)(d & (BC-1));
    int pos = atomicAdd(&bcur[w*BKT + b], 1);
    if ((unsigned)pos < NE)                               // never store OOB
        binned[(size_t)w*NE + pos] = (dl << 17) | (int)s;
}

// ---------------- matmul: out[r] = (in[r] * scale[r]) @ W (+ bias) ----------------
template<bool HAS_BIAS>
__global__ __launch_bounds__(256) void matmul_kernel(
        const float* __restrict__ in, float* __restrict__ out,
        const float* __restrict__ wmat, const float* __restrict__ scale,
        const float* __restrict__ bias) {
    __shared__ float wlds[NF*NF];     // 64 KB: full 128x128 weight
    __shared__ float alds[32*NF];     // 16 KB: 32 staged rows
    for (int i = threadIdx.x; i < NF*NF/4; i += 256)
        ((float4*)wlds)[i] = ((const float4*)wmat)[i];
    __syncthreads();

    int cg = threadIdx.x & 31;        // col group (float4 -> cols cg*4..cg*4+3)
    int rg = threadIdx.x >> 5;        // 0..7 row group (rows rg*4..rg*4+3)
    int rowbase = blockIdx.x * 128;   // 128 rows per block

    for (int pass = 0; pass < 4; ++pass) {
        int r0 = rowbase + pass*32;
        for (int i = threadIdx.x; i < 32*NF/4; i += 256) {
            int row = i >> 5;
            float sc = scale[r0 + row];
            float4 v = ((const float4*)(in + (size_t)r0*NF))[i];
            v.x *= sc; v.y *= sc; v.z *= sc; v.w *= sc;
            ((float4*)alds)[i] = v;
        }
        __syncthreads();

        float4 acc0 = {0,0,0,0}, acc1 = {0,0,0,0}, acc2 = {0,0,0,0}, acc3 = {0,0,0,0};
        const float* a0 = alds + (rg*4+0)*NF;
        const float* a1 = alds + (rg*4+1)*NF;
        const float* a2 = alds + (rg*4+2)*NF;
        const float* a3 = alds + (rg*4+3)*NF;
        for (int k = 0; k < NF; ++k) {
            float4 wv = ((const float4*)(wlds + k*NF))[cg];
            float b0 = a0[k], b1 = a1[k], b2 = a2[k], b3 = a3[k];
            acc0.x += wv.x*b0; acc0.y += wv.y*b0; acc0.z += wv.z*b0; acc0.w += wv.w*b0;
            acc1.x += wv.x*b1; acc1.y += wv.y*b1; acc1.z += wv.z*b1; acc1.w += wv.w*b1;
            acc2.x += wv.x*b2; acc2.y += wv.y*b2; acc2.z += wv.z*b2; acc2.w += wv.w*b2;
            acc3.x += wv.x*b3; acc3.y += wv.y*b3; acc3.z += wv.z*b3; acc3.w += wv.w*b3;
        }
        if (HAS_BIAS) {
            float4 b = ((const float4*)bias)[cg];
            acc0.x += b.x; acc0.y += b.y; acc0.z += b.z; acc0.w += b.w;
            acc1.x += b.x; acc1.y += b.y; acc1.z += b.z; acc1.w += b.w;
            acc2.x += b.x; acc2.y += b.y; acc2.z += b.z; acc2.w += b.w;
            acc3.x += b.x; acc3.y += b.y; acc3.z += b.z; acc3.w += b.w;
        }
        ((float4*)(out + (size_t)(r0 + rg*4+0)*NF))[cg] = acc0;
        ((float4*)(out + (size_t)(r0 + rg*4+1)*NF))[cg] = acc1;
        ((float4*)(out + (size_t)(r0 + rg*4+2)*NF))[cg] = acc2;
        ((float4*)(out + (size_t)(r0 + rg*4+3)*NF))[cg] = acc3;
        __syncthreads();
    }
}

// ---------------- bucket gather: LDS accumulator for 64 dst nodes ----------------
// One 256-thread block per (worker, bucket). Edge list for the bucket is read
// sequentially (coalesced); P rows random-read (LLC-resident); accumulation via
// ds_add_f32 into a column-swizzled LDS layout (elem 4c+j stored at j*32+c ->
// bank == lane, conflict-free). Epilogue: fused inv_in scale + bias, coalesced.
__global__ __launch_bounds__(256) void bucket_gather_kernel(
        const float* __restrict__ P, const float* __restrict__ inv_in,
        const int* __restrict__ row_start, const int* __restrict__ binned,
        const float* __restrict__ bias, float* __restrict__ out) {
    __shared__ float acc[BC*NF];                      // 32 KB
    int w = blockIdx.y, b = blockIdx.x;
    int tid = threadIdx.x;
    int hw = tid >> 5;                                // half-wave id 0..7
    int c  = tid & 31;                                // float4 column group

    // zero accumulator
    for (int i = tid; i < BC*NF/4; i += 256)
        ((float4*)acc)[i] = make_float4(0.f, 0.f, 0.f, 0.f);
    __syncthreads();

    int beg = row_start[w*NN + (b<<BSH)];
    int end = (b == BKT-1) ? NE : row_start[w*NN + ((b+1)<<BSH)];
    const int* bb = binned + (size_t)w*NE;
    const float4* p4 = (const float4*)P;
    size_t wbase = (size_t)w*NN;

    int e = beg + hw;
    for (; e + 8 < end; e += 16) {                    // 2 edges per iteration
        unsigned pk0 = (unsigned)bb[e];
        unsigned pk1 = (unsigned)bb[e+8];
        int s0 = pk0 & 0x1FFFF, dl0 = pk0 >> 17;
        int s1 = pk1 & 0x1FFFF, dl1 = pk1 >> 17;
        float4 v0 = p4[(wbase + s0)*32 + c];
        float4 v1 = p4[(wbase + s1)*32 + c];
        int a0 = dl0*NF + c, a1 = dl1*NF + c;
        atomicAdd(&acc[a0     ], v0.x);
        atomicAdd(&acc[a0 + 32], v0.y);
        atomicAdd(&acc[a0 + 64], v0.z);
        atomicAdd(&acc[a0 + 96], v0.w);
        atomicAdd(&acc[a1     ], v1.x);
        atomicAdd(&acc[a1 + 32], v1.y);
        atomicAdd(&acc[a1 + 64], v1.z);
        atomicAdd(&acc[a1 + 96], v1.w);
    }
    if (e < end) {
        unsigned pk = (unsigned)bb[e];
        int s = pk & 0x1FFFF, dl = pk >> 17;
        float4 v = p4[(wbase + s)*32 + c];
        int a = dl*NF + c;
        atomicAdd(&acc[a     ], v.x);
        atomicAdd(&acc[a + 32], v.y);
        atomicAdd(&acc[a + 64], v.z);
        atomicAdd(&acc[a + 96], v.w);
    }
    __syncthreads();

    // write out 64 rows, fused scale + bias
    float4 bv = ((const float4*)bias)[c];
    int row = tid >> 5;                               // 0..7
    for (int k = 0; k < 8; ++k) {
        int r = k*8 + row;
        int node = (b<<BSH) + r;
        if (node < NN) {
            float sc = inv_in[w*NN + node];
            float4 o;
            o.x = acc[r*NF +       c] * sc + bv.x;
            o.y = acc[r*NF + 32 +  c] * sc + bv.y;
            o.z = acc[r*NF + 64 +  c] * sc + bv.z;
            o.w = acc[r*NF + 96 +  c] * sc + bv.w;
            ((float4*)out)[(wbase + node)*32 + c] = o;
        }
    }
}

// ---------------- fallback path (ws too small for P): per-node CSR + float2 gather ----------------
__global__ void cursor_copy_kernel(const int* __restrict__ row_start, int* __restrict__ cursor) {
    int i = blockIdx.x * blockDim.x + threadIdx.x;
    if (i < WN) cursor[i] = row_start[i];
}

__global__ void place_kernel(const int* __restrict__ src, const int* __restrict__ dst,
                             int* __restrict__ cursor, int* __restrict__ sorted) {
    int w = blockIdx.y;
    int i = blockIdx.x * blockDim.x + threadIdx.x;
    if (i >= NE) return;
    unsigned s = (unsigned)src[(size_t)w*NE + i];
    unsigned d = (unsigned)dst[(size_t)w*NE + i];
    if (s >= NN || d >= NN) return;
    int pos = atomicAdd(&cursor[w*NN + (int)d], 1);
    if ((unsigned)pos < NE)
        sorted[(size_t)w*NE + pos] = (int)s;
}

__global__ __launch_bounds__(256) void gather_fallback_kernel(
        const float* __restrict__ feats, const float* __restrict__ inv_out,
        const int* __restrict__ row_start, const int* __restrict__ deg_in,
        const int* __restrict__ sorted, float* __restrict__ agg) {
    int g    = blockIdx.x * 4 + (threadIdx.x >> 6);
    int lane = threadIdx.x & 63;
    int w    = g / NN;
    int beg  = row_start[g];
    int end  = beg + deg_in[g];
    const int*    ss = sorted + (size_t)w*NE;
    const float2* f2 = (const float2*)feats;
    float ax = 0.f, ay = 0.f;
    for (int e = beg; e < end; ++e) {
        int s = ss[e];
        float sc = inv_out[w*NN + s];
        float2 v = f2[((size_t)(w*NN + s))*64 + lane];
        ax += v.x * sc;
        ay += v.y * sc;
    }
    ((float2*)agg)[(size_t)g*64 + lane] = make_float2(ax, ay);
}

extern "C" void kernel_launch(void* const* d_in, const int* in_sizes, int n_in,
                              void* d_out, int out_size, void* d_ws, size_t ws_size,
                              hipStream_t stream) {
    const float* feats = (const float*)d_in[0];
    const float* wmat  = (const float*)d_in[1];
    const float* bias  = (const float*)d_in[2];
    const int*   src   = (const int*)d_in[3];
    const int*   dst   = (const int*)d_in[4];
    float* out = (float*)d_out;

    // workspace layout (ints unless noted) — byte-identical size to prev round:
    //   cnt_out[WN] cnt_in[WN] row_start[WN] cursor/bcur[WN]
    //   inv_out(f32)[WN] inv_in(f32)[WN] partials[1024] binned/sorted[WK*NE] P(f32)[WN*NF]
    int* ws        = (int*)d_ws;
    int* cnt_out   = ws;
    int* cnt_in    = ws + WN;
    int* row_start = ws + 2*WN;
    int* cursor    = ws + 3*WN;                 // fallback: per-node cursors; fast path: bcur
    int* bcur      = cursor;                    // WK*BKT = 6252 ints, fits easily
    float* inv_out = (float*)(ws + 4*WN);
    float* inv_in  = (float*)(ws + 5*WN);
    int* partials  = ws + 6*WN;                 // W*TPW ints, padded to 1024
    int* binned    = ws + 6*WN + 1024;          // W*NE ints (aka sorted in fallback)
    float* P       = (float*)(binned + (size_t)WK*NE);  // WN*NF floats

    size_t csr_bytes = ((size_t)6*WN + 1024 + (size_t)WK*NE) * sizeof(int);
    size_t p_bytes   = (size_t)WN * NF * sizeof(float);
    bool use_csr = ws_size >= csr_bytes;
    bool use_p   = ws_size >= csr_bytes + p_bytes;

    hipMemsetAsync(cnt_out, 0, (size_t)2*WN*sizeof(int), stream);
    deg_kernel<<<dim3(NE/256, WK), 256, 0, stream>>>(src, dst, cnt_out, cnt_in);

    if (use_csr) {
        scan1_kernel<<<dim3(TPW, WK), TILE, 0, stream>>>(cnt_in, row_start, partials);
        scan2_kernel<<<WK, 256, 0, stream>>>(partials);
        scan3_kernel<<<dim3(TPW, WK), TILE, 0, stream>>>(row_start, partials);
        finalize_kernel<<<(WN+255)/256, 256, 0, stream>>>(cnt_out, cnt_in, inv_out, inv_in);
        if (use_p) {
            bucket_init_kernel<<<(WK*BKT+255)/256, 256, 0, stream>>>(row_start, bcur);
            bin_kernel<<<dim3(NE/256, WK), 256, 0, stream>>>(src, dst, bcur, binned);
            // P = diag(inv_out) X W   (projection before aggregation)
            matmul_kernel<false><<<WN/128, 256, 0, stream>>>(
                feats, P, wmat, inv_out, nullptr);
            bucket_gather_kernel<<<dim3(BKT, WK), 256, 0, stream>>>(
                P, inv_in, row_start, binned, bias, out);
        } else {
            cursor_copy_kernel<<<(WN+255)/256, 256, 0, stream>>>(row_start, cursor);
            place_kernel<<<dim3(NE/256, WK), 256, 0, stream>>>(src, dst, cursor, binned);
            gather_fallback_kernel<<<WN/4, 256, 0, stream>>>(
                feats, inv_out, row_start, cnt_in, binned, out);
            matmul_kernel<true><<<WN/128, 256, 0, stream>>>(
                out, out, wmat, inv_in, bias);
        }
    } else {
        // emergency: shouldn't happen (ws known >= csr from round 1)
        finalize_kernel<<<(WN+255)/256, 256, 0, stream>>>(cnt_out, cnt_in, inv_out, inv_in);
        hipMemsetAsync(out, 0, (size_t)WN*NF*sizeof(float), stream);
        matmul_kernel<true><<<WN/128, 256, 0, stream>>>(
            out, out, wmat, inv_in, bias);
    }
}

// Round 3
// 1830.001 us; speedup vs baseline: 3.3107x; 3.3107x over previous
//
#include <hip/hip_runtime.h>
#include <cstdint>

#define WK 4
#define NN 100000
#define NE 1600000
#define NF 128
#define WN (WK*NN)                    // 400000
#define TILE 512
#define TPW ((NN + TILE - 1)/TILE)    // 196 tiles per worker
#define B3  (NN/8)                    // 12500 8-node bin buckets per worker (exact)
#define GC  64                        // nodes per gather group
#define NG  ((NN + GC - 1)/GC)        // 1563 groups per worker
#define CAP 2048                      // LDS edge chunk

// ---------------- degree counting ----------------
__global__ void deg_kernel(const int* __restrict__ src, const int* __restrict__ dst,
                           int* __restrict__ cnt_out, int* __restrict__ cnt_in) {
    int w = blockIdx.y;
    int i = blockIdx.x * blockDim.x + threadIdx.x;
    if (i >= NE) return;
    unsigned s = (unsigned)src[(size_t)w*NE + i];
    unsigned d = (unsigned)dst[(size_t)w*NE + i];
    if (s < NN) atomicAdd(&cnt_out[w*NN + (int)s], 1);
    if (d < NN) atomicAdd(&cnt_in [w*NN + (int)d], 1);
}

// ---------------- prefix scan (3 kernels) over cnt_in -> row_start ----------------
__global__ void scan1_kernel(const int* __restrict__ cnt_in, int* __restrict__ row_start,
                             int* __restrict__ partials) {
    __shared__ int sdata[TILE];
    int w = blockIdx.y, t = blockIdx.x, tid = threadIdx.x;
    int g = t*TILE + tid;
    int v = (g < NN) ? cnt_in[w*NN + g] : 0;
    sdata[tid] = v;
    __syncthreads();
    for (int off = 1; off < TILE; off <<= 1) {
        int tmp = (tid >= off) ? sdata[tid - off] : 0;
        __syncthreads();
        sdata[tid] += tmp;
        __syncthreads();
    }
    if (tid == TILE-1) partials[w*TPW + t] = sdata[TILE-1];
    if (g < NN) row_start[w*NN + g] = sdata[tid] - v;   // exclusive within tile
}

__global__ void scan2_kernel(int* __restrict__ partials) {
    __shared__ int sdata[256];
    int w = blockIdx.x, tid = threadIdx.x;
    int v = (tid < TPW) ? partials[w*TPW + tid] : 0;
    sdata[tid] = v;
    __syncthreads();
    for (int off = 1; off < 256; off <<= 1) {
        int tmp = (tid >= off) ? sdata[tid - off] : 0;
        __syncthreads();
        sdata[tid] += tmp;
        __syncthreads();
    }
    if (tid < TPW) partials[w*TPW + tid] = sdata[tid] - v;  // exclusive tile offsets
}

__global__ void scan3_kernel(int* __restrict__ row_start, const int* __restrict__ partials) {
    int w = blockIdx.y, t = blockIdx.x, tid = threadIdx.x;
    int g = t*TILE + tid;
    if (g >= NN) return;
    row_start[w*NN + g] += partials[w*TPW + t];
}

// ---------------- counts -> rsqrt(max(deg,1)) into SEPARATE float arrays ----------------
__global__ void finalize_kernel(const int* __restrict__ cnt_out, const int* __restrict__ cnt_in,
                                float* __restrict__ inv_out, float* __restrict__ inv_in) {
    int i = blockIdx.x * blockDim.x + threadIdx.x;
    if (i >= WN) return;
    inv_out[i] = rsqrtf(fmaxf((float)cnt_out[i], 1.0f));
    inv_in [i] = rsqrtf(fmaxf((float)cnt_in [i], 1.0f));
}

// ---------------- bin cursors: bcur[w][j] = row_start[w, j*8] ----------------
__global__ void bucket_init_kernel(const int* __restrict__ row_start, int* __restrict__ bcur) {
    int i = blockIdx.x * blockDim.x + threadIdx.x;
    if (i >= WK*B3) return;
    int w = i / B3, j = i % B3;
    bcur[i] = row_start[w*NN + j*8];
}

// ---------------- bin edges into 8-node buckets: binned[pos] = ((d&63)<<17)|src ----
// 50K cursors/4 workers -> 128-way contention per cursor (vs 1024 @ 64-node buckets,
// the round-2 bottleneck). Write windows 512B, appends sequential -> LLC absorbs.
__global__ void bin_kernel(const int* __restrict__ src, const int* __restrict__ dst,
                           int* __restrict__ bcur, int* __restrict__ binned) {
    int w = blockIdx.y;
    int i = blockIdx.x * blockDim.x + threadIdx.x;
    if (i >= NE) return;
    unsigned s = (unsigned)src[(size_t)w*NE + i];
    unsigned d = (unsigned)dst[(size_t)w*NE + i];
    if (s >= NN || d >= NN) return;                       // never index from garbage
    int pos = atomicAdd(&bcur[w*B3 + (int)(d >> 3)], 1);
    if ((unsigned)pos < NE)                               // never store OOB
        binned[(size_t)w*NE + pos] = ((int)(d & 63) << 17) | (int)s;
}

// ---------------- matmul: out[r] = (in[r] * scale[r]) @ W (+ bias) ----------------
template<bool HAS_BIAS>
__global__ __launch_bounds__(256) void matmul_kernel(
        const float* __restrict__ in, float* __restrict__ out,
        const float* __restrict__ wmat, const float* __restrict__ scale,
        const float* __restrict__ bias) {
    __shared__ float wlds[NF*NF];     // 64 KB: full 128x128 weight
    __shared__ float alds[32*NF];     // 16 KB: 32 staged rows
    for (int i = threadIdx.x; i < NF*NF/4; i += 256)
        ((float4*)wlds)[i] = ((const float4*)wmat)[i];
    __syncthreads();

    int cg = threadIdx.x & 31;
    int rg = threadIdx.x >> 5;
    int rowbase = blockIdx.x * 128;

    for (int pass = 0; pass < 4; ++pass) {
        int r0 = rowbase + pass*32;
        for (int i = threadIdx.x; i < 32*NF/4; i += 256) {
            int row = i >> 5;
            float sc = scale[r0 + row];
            float4 v = ((const float4*)(in + (size_t)r0*NF))[i];
            v.x *= sc; v.y *= sc; v.z *= sc; v.w *= sc;
            ((float4*)alds)[i] = v;
        }
        __syncthreads();

        float4 acc0 = {0,0,0,0}, acc1 = {0,0,0,0}, acc2 = {0,0,0,0}, acc3 = {0,0,0,0};
        const float* a0 = alds + (rg*4+0)*NF;
        const float* a1 = alds + (rg*4+1)*NF;
        const float* a2 = alds + (rg*4+2)*NF;
        const float* a3 = alds + (rg*4+3)*NF;
        for (int k = 0; k < NF; ++k) {
            float4 wv = ((const float4*)(wlds + k*NF))[cg];
            float b0 = a0[k], b1 = a1[k], b2 = a2[k], b3 = a3[k];
            acc0.x += wv.x*b0; acc0.y += wv.y*b0; acc0.z += wv.z*b0; acc0.w += wv.w*b0;
            acc1.x += wv.x*b1; acc1.y += wv.y*b1; acc1.z += wv.z*b1; acc1.w += wv.w*b1;
            acc2.x += wv.x*b2; acc2.y += wv.y*b2; acc2.z += wv.z*b2; acc2.w += wv.w*b2;
            acc3.x += wv.x*b3; acc3.y += wv.y*b3; acc3.z += wv.z*b3; acc3.w += wv.w*b3;
        }
        if (HAS_BIAS) {
            float4 b = ((const float4*)bias)[cg];
            acc0.x += b.x; acc0.y += b.y; acc0.z += b.z; acc0.w += b.w;
            acc1.x += b.x; acc1.y += b.y; acc1.z += b.z; acc1.w += b.w;
            acc2.x += b.x; acc2.y += b.y; acc2.z += b.z; acc2.w += b.w;
            acc3.x += b.x; acc3.y += b.y; acc3.z += b.z; acc3.w += b.w;
        }
        ((float4*)(out + (size_t)(r0 + rg*4+0)*NF))[cg] = acc0;
        ((float4*)(out + (size_t)(r0 + rg*4+1)*NF))[cg] = acc1;
        ((float4*)(out + (size_t)(r0 + rg*4+2)*NF))[cg] = acc2;
        ((float4*)(out + (size_t)(r0 + rg*4+3)*NF))[cg] = acc3;
        __syncthreads();
    }
}

// ---------------- fused LDS counting-sort + register gather ----------------
// One 256-thread block per 64-node group. The group's binned edges are a
// CONTIGUOUS range [row_start[n0], row_start[n0+64]). Chunks of <=2048 edges are
// counting-sorted by d&63 in LDS (INTEGER ds atomics only — native, fast), then
// each of the 4 waves accumulates its 16 nodes' P rows in registers (no float
// atomics anywhere). Epilogue: cross-half reduce + fused inv_in scale + bias.
__global__ __launch_bounds__(256) void sortgather_kernel(
        const float* __restrict__ P, const float* __restrict__ inv_in,
        const int* __restrict__ row_start, const int* __restrict__ binned,
        const float* __restrict__ bias, float* __restrict__ out) {
    __shared__ int ecnt[GC];
    __shared__ int eoff[GC];
    __shared__ int ecur[GC];
    __shared__ int elraw[CAP];
    __shared__ int elist[CAP];

    int w = blockIdx.y, g = blockIdx.x;
    int tid  = threadIdx.x;
    int wave = tid >> 6;              // 0..3
    int half = (tid >> 5) & 1;
    int c    = tid & 31;

    int n0  = g << 6;
    int beg = row_start[w*NN + n0];
    int end = (g == NG-1) ? NE : row_start[w*NN + n0 + GC];

    const int* bb = binned + (size_t)w*NE;
    const float4* p4 = (const float4*)P;
    size_t wbase = (size_t)w*NN;

    float4 acc[16];
    #pragma unroll
    for (int n = 0; n < 16; ++n) acc[n] = make_float4(0.f,0.f,0.f,0.f);

    for (int cb = beg; cb < end; cb += CAP) {
        int m = end - cb; if (m > CAP) m = CAP;
        if (tid < GC) ecnt[tid] = 0;
        __syncthreads();
        // stage + histogram (int LDS atomics: native ds_add)
        for (int i = tid; i < m; i += 256) {
            int pk = bb[cb + i];
            elraw[i] = pk;
            atomicAdd(&ecnt[(pk >> 17) & 63], 1);
        }
        __syncthreads();
        // exclusive scan of 64 counters (wave 0)
        if (tid < 64) {
            int v = ecnt[tid];
            int x = v;
            #pragma unroll
            for (int o = 1; o < 64; o <<= 1) {
                int t = __shfl_up(x, o);
                if (tid >= o) x += t;
            }
            eoff[tid] = x - v;
            ecur[tid] = x - v;
        }
        __syncthreads();
        // scatter into per-node contiguous LDS lists (clamp src: fault-proof)
        for (int i = tid; i < m; i += 256) {
            int pk = elraw[i];
            int dl = (pk >> 17) & 63;
            int pos = atomicAdd(&ecur[dl], 1);
            int s = pk & 0x1FFFF;
            elist[pos] = (s < NN) ? s : (NN-1);
        }
        __syncthreads();
        // per-wave register accumulation: wave owns nodes wave*16 .. wave*16+15
        #pragma unroll
        for (int n = 0; n < 16; ++n) {
            int nl  = wave*16 + n;
            int off = eoff[nl];
            int fin = off + ecnt[nl];
            int e = off;
            for (; e + 3 < fin; e += 4) {
                int s0 = elist[e + half*2];
                int s1 = elist[e + half*2 + 1];
                float4 v0 = p4[(wbase + s0)*32 + c];
                float4 v1 = p4[(wbase + s1)*32 + c];
                acc[n].x += v0.x + v1.x; acc[n].y += v0.y + v1.y;
                acc[n].z += v0.z + v1.z; acc[n].w += v0.w + v1.w;
            }
            for (; e < fin; e += 2) {
                int ee = e + half;
                if (ee < fin) {
                    int s = elist[ee];
                    float4 v = p4[(wbase + s)*32 + c];
                    acc[n].x += v.x; acc[n].y += v.y;
                    acc[n].z += v.z; acc[n].w += v.w;
                }
            }
        }
        __syncthreads();
    }

    // epilogue: cross-half reduce, scale, bias, coalesced write
    float4 bv = ((const float4*)bias)[c];
    #pragma unroll
    for (int n = 0; n < 16; ++n) {
        float4 a = acc[n];
        a.x += __shfl_down(a.x, 32);
        a.y += __shfl_down(a.y, 32);
        a.z += __shfl_down(a.z, 32);
        a.w += __shfl_down(a.w, 32);
        if (half == 0) {
            int node = n0 + wave*16 + n;
            if (node < NN) {
                float sc = inv_in[w*NN + node];
                float4 o;
                o.x = a.x*sc + bv.x; o.y = a.y*sc + bv.y;
                o.z = a.z*sc + bv.z; o.w = a.w*sc + bv.w;
                ((float4*)out)[(wbase + node)*32 + c] = o;
            }
        }
    }
}

// ---------------- fallback path (ws too small for P): per-node CSR + float2 gather ----------------
__global__ void cursor_copy_kernel(const int* __restrict__ row_start, int* __restrict__ cursor) {
    int i = blockIdx.x * blockDim.x + threadIdx.x;
    if (i < WN) cursor[i] = row_start[i];
}

__global__ void place_kernel(const int* __restrict__ src, const int* __restrict__ dst,
                             int* __restrict__ cursor, int* __restrict__ sorted) {
    int w = blockIdx.y;
    int i = blockIdx.x * blockDim.x + threadIdx.x;
    if (i >= NE) return;
    unsigned s = (unsigned)src[(size_t)w*NE + i];
    unsigned d = (unsigned)dst[(size_t)w*NE + i];
    if (s >= NN || d >= NN) return;
    int pos = atomicAdd(&cursor[w*NN + (int)d], 1);
    if ((unsigned)pos < NE)
        sorted[(size_t)w*NE + pos] = (int)s;
}

__global__ __launch_bounds__(256) void gather_fallback_kernel(
        const float* __restrict__ feats, const float* __restrict__ inv_out,
        const int* __restrict__ row_start, const int* __restrict__ deg_in,
        const int* __restrict__ sorted, float* __restrict__ agg) {
    int g    = blockIdx.x * 4 + (threadIdx.x >> 6);
    int lane = threadIdx.x & 63;
    int w    = g / NN;
    int beg  = row_start[g];
    int end  = beg + deg_in[g];
    const int*    ss = sorted + (size_t)w*NE;
    const float2* f2 = (const float2*)feats;
    float ax = 0.f, ay = 0.f;
    for (int e = beg; e < end; ++e) {
        int s = ss[e];
        float sc = inv_out[w*NN + s];
        float2 v = f2[((size_t)(w*NN + s))*64 + lane];
        ax += v.x * sc;
        ay += v.y * sc;
    }
    ((float2*)agg)[(size_t)g*64 + lane] = make_float2(ax, ay);
}

extern "C" void kernel_launch(void* const* d_in, const int* in_sizes, int n_in,
                              void* d_out, int out_size, void* d_ws, size_t ws_size,
                              hipStream_t stream) {
    const float* feats = (const float*)d_in[0];
    const float* wmat  = (const float*)d_in[1];
    const float* bias  = (const float*)d_in[2];
    const int*   src   = (const int*)d_in[3];
    const int*   dst   = (const int*)d_in[4];
    float* out = (float*)d_out;

    // workspace layout (ints unless noted):
    //   cnt_out[WN] cnt_in[WN] row_start[WN] cursor/bcur[WN]
    //   inv_out(f32)[WN] inv_in(f32)[WN] partials[1024] binned/sorted[WK*NE] P(f32)[WN*NF]
    int* ws        = (int*)d_ws;
    int* cnt_out   = ws;
    int* cnt_in    = ws + WN;
    int* row_start = ws + 2*WN;
    int* cursor    = ws + 3*WN;                 // fast path: bcur (WK*B3 = 50000 ints)
    int* bcur      = cursor;
    float* inv_out = (float*)(ws + 4*WN);
    float* inv_in  = (float*)(ws + 5*WN);
    int* partials  = ws + 6*WN;                 // W*TPW ints, padded to 1024
    int* binned    = ws + 6*WN + 1024;          // W*NE ints (aka sorted in fallback)
    float* P       = (float*)(binned + (size_t)WK*NE);  // WN*NF floats

    size_t csr_bytes = ((size_t)6*WN + 1024 + (size_t)WK*NE) * sizeof(int);
    size_t p_bytes   = (size_t)WN * NF * sizeof(float);
    bool use_csr = ws_size >= csr_bytes;
    bool use_p   = ws_size >= csr_bytes + p_bytes;

    hipMemsetAsync(cnt_out, 0, (size_t)2*WN*sizeof(int), stream);
    deg_kernel<<<dim3(NE/256, WK), 256, 0, stream>>>(src, dst, cnt_out, cnt_in);

    if (use_csr) {
        scan1_kernel<<<dim3(TPW, WK), TILE, 0, stream>>>(cnt_in, row_start, partials);
        scan2_kernel<<<WK, 256, 0, stream>>>(partials);
        scan3_kernel<<<dim3(TPW, WK), TILE, 0, stream>>>(row_start, partials);
        finalize_kernel<<<(WN+255)/256, 256, 0, stream>>>(cnt_out, cnt_in, inv_out, inv_in);
        if (use_p) {
            bucket_init_kernel<<<(WK*B3+255)/256, 256, 0, stream>>>(row_start, bcur);
            bin_kernel<<<dim3(NE/256, WK), 256, 0, stream>>>(src, dst, bcur, binned);
            // P = diag(inv_out) X W   (projection before aggregation)
            matmul_kernel<false><<<WN/128, 256, 0, stream>>>(
                feats, P, wmat, inv_out, nullptr);
            sortgather_kernel<<<dim3(NG, WK), 256, 0, stream>>>(
                P, inv_in, row_start, binned, bias, out);
        } else {
            cursor_copy_kernel<<<(WN+255)/256, 256, 0, stream>>>(row_start, cursor);
            place_kernel<<<dim3(NE/256, WK), 256, 0, stream>>>(src, dst, cursor, binned);
            gather_fallback_kernel<<<WN/4, 256, 0, stream>>>(
                feats, inv_out, row_start, cnt_in, binned, out);
            matmul_kernel<true><<<WN/128, 256, 0, stream>>>(
                out, out, wmat, inv_in, bias);
        }
    } else {
        // emergency: shouldn't happen (ws known >= csr from round 1)
        finalize_kernel<<<(WN+255)/256, 256, 0, stream>>>(cnt_out, cnt_in, inv_out, inv_in);
        hipMemsetAsync(out, 0, (size_t)WN*NF*sizeof(float), stream);
        matmul_kernel<true><<<WN/128, 256, 0, stream>>>(
            out, out, wmat, inv_in, bias);
    }
}

// Round 4
// 1479.293 us; speedup vs baseline: 4.0956x; 1.2371x over previous
//
#include <hip/hip_runtime.h>
#include <cstdint>

#define WK 4
#define NN 100000
#define NE 1600000
#define NF 128
#define WN (WK*NN)                    // 400000
#define TILE 512
#define TPW ((NN + TILE - 1)/TILE)    // 196 tiles per worker
#define B3  (NN/8)                    // 12500 8-node bin buckets per worker (exact)
#define GC  64                        // nodes per gather group
#define NG  ((NN + GC - 1)/GC)        // 1563 groups per worker
#define CAP 2048                      // LDS edge chunk
// histogram partitioning
#define HR    20000                   // nodes per histogram range (80 KB LDS)
#define NRANGE 5                      // 5 * 20000 = 100000 = NN
#define NSEG   8                      // edge segments per worker
#define SEGSZ (NE/NSEG)               // 200000

// ---------------- OLD atomic degree counting (fallback path only) ----------------
__global__ void deg_kernel(const int* __restrict__ src, const int* __restrict__ dst,
                           int* __restrict__ cnt_out, int* __restrict__ cnt_in) {
    int w = blockIdx.y;
    int i = blockIdx.x * blockDim.x + threadIdx.x;
    if (i >= NE) return;
    unsigned s = (unsigned)src[(size_t)w*NE + i];
    unsigned d = (unsigned)dst[(size_t)w*NE + i];
    if (s < NN) atomicAdd(&cnt_out[w*NN + (int)s], 1);
    if (d < NN) atomicAdd(&cnt_in [w*NN + (int)d], 1);
}

// ---------------- LDS-privatized histogram: zero global atomics ----------------
// block = (seg, range) x (worker) x (array: 0=src->cnt_out, 1=dst->cnt_in).
// Streams its 200K-edge segment (int4), LDS int atomics for keys in range,
// dumps the range slice coalesced into partials[(w*2+arr)*NSEG+seg][NN].
__global__ __launch_bounds__(256) void hist_kernel(
        const int* __restrict__ src, const int* __restrict__ dst,
        int* __restrict__ partials) {
    __shared__ int h[HR];                               // 80 KB
    int seg = blockIdx.x / NRANGE;
    int rng = blockIdx.x % NRANGE;
    int w   = blockIdx.y;
    int arr = blockIdx.z;
    int tid = threadIdx.x;

    const int* idxp = (arr ? dst : src) + (size_t)w*NE + (size_t)seg*SEGSZ;
    int r0 = rng * HR;

    for (int i = tid; i < HR; i += 256) h[i] = 0;
    __syncthreads();

    const int4* v4 = (const int4*)idxp;
    for (int i = tid; i < SEGSZ/4; i += 256) {
        int4 v = v4[i];
        unsigned a = (unsigned)(v.x - r0);
        unsigned b = (unsigned)(v.y - r0);
        unsigned c = (unsigned)(v.z - r0);
        unsigned d = (unsigned)(v.w - r0);
        if (a < HR) atomicAdd(&h[a], 1);
        if (b < HR) atomicAdd(&h[b], 1);
        if (c < HR) atomicAdd(&h[c], 1);
        if (d < HR) atomicAdd(&h[d], 1);
    }
    __syncthreads();

    int* pp = partials + ((size_t)(w*2 + arr)*NSEG + seg)*NN + r0;
    for (int i = tid; i < HR; i += 256) pp[i] = h[i];   // coalesced, non-atomic
}

// cnt[w][arr][node] = sum over segments
__global__ void reduce_kernel(const int* __restrict__ partials,
                              int* __restrict__ cnt_out, int* __restrict__ cnt_in) {
    int i = blockIdx.x * blockDim.x + threadIdx.x;
    if (i >= 2*WN) return;
    int w    = i / (2*NN);
    int rem  = i - w*2*NN;
    int arr  = rem / NN;
    int node = rem - arr*NN;
    const int* pp = partials + ((size_t)(w*2 + arr)*NSEG)*NN + node;
    int sum = 0;
    #pragma unroll
    for (int s = 0; s < NSEG; ++s) sum += pp[(size_t)s*NN];
    if (arr) cnt_in [w*NN + node] = sum;
    else     cnt_out[w*NN + node] = sum;
}

// ---------------- prefix scan (3 kernels) over cnt_in -> row_start ----------------
__global__ void scan1_kernel(const int* __restrict__ cnt_in, int* __restrict__ row_start,
                             int* __restrict__ partials) {
    __shared__ int sdata[TILE];
    int w = blockIdx.y, t = blockIdx.x, tid = threadIdx.x;
    int g = t*TILE + tid;
    int v = (g < NN) ? cnt_in[w*NN + g] : 0;
    sdata[tid] = v;
    __syncthreads();
    for (int off = 1; off < TILE; off <<= 1) {
        int tmp = (tid >= off) ? sdata[tid - off] : 0;
        __syncthreads();
        sdata[tid] += tmp;
        __syncthreads();
    }
    if (tid == TILE-1) partials[w*TPW + t] = sdata[TILE-1];
    if (g < NN) row_start[w*NN + g] = sdata[tid] - v;   // exclusive within tile
}

__global__ void scan2_kernel(int* __restrict__ partials) {
    __shared__ int sdata[256];
    int w = blockIdx.x, tid = threadIdx.x;
    int v = (tid < TPW) ? partials[w*TPW + tid] : 0;
    sdata[tid] = v;
    __syncthreads();
    for (int off = 1; off < 256; off <<= 1) {
        int tmp = (tid >= off) ? sdata[tid - off] : 0;
        __syncthreads();
        sdata[tid] += tmp;
        __syncthreads();
    }
    if (tid < TPW) partials[w*TPW + tid] = sdata[tid] - v;  // exclusive tile offsets
}

__global__ void scan3_kernel(int* __restrict__ row_start, const int* __restrict__ partials) {
    int w = blockIdx.y, t = blockIdx.x, tid = threadIdx.x;
    int g = t*TILE + tid;
    if (g >= NN) return;
    row_start[w*NN + g] += partials[w*TPW + t];
}

// ---------------- counts -> rsqrt(max(deg,1)) into SEPARATE float arrays ----------------
__global__ void finalize_kernel(const int* __restrict__ cnt_out, const int* __restrict__ cnt_in,
                                float* __restrict__ inv_out, float* __restrict__ inv_in) {
    int i = blockIdx.x * blockDim.x + threadIdx.x;
    if (i >= WN) return;
    inv_out[i] = rsqrtf(fmaxf((float)cnt_out[i], 1.0f));
    inv_in [i] = rsqrtf(fmaxf((float)cnt_in [i], 1.0f));
}

// ---------------- bin cursors: bcur[w][j] = row_start[w, j*8] ----------------
__global__ void bucket_init_kernel(const int* __restrict__ row_start, int* __restrict__ bcur) {
    int i = blockIdx.x * blockDim.x + threadIdx.x;
    if (i >= WK*B3) return;
    int w = i / B3, j = i % B3;
    bcur[i] = row_start[w*NN + j*8];
}

// ---------------- bin edges into 8-node buckets: binned[pos] = ((d&63)<<17)|src ----
__global__ void bin_kernel(const int* __restrict__ src, const int* __restrict__ dst,
                           int* __restrict__ bcur, int* __restrict__ binned) {
    int w = blockIdx.y;
    int i = blockIdx.x * blockDim.x + threadIdx.x;
    if (i >= NE) return;
    unsigned s = (unsigned)src[(size_t)w*NE + i];
    unsigned d = (unsigned)dst[(size_t)w*NE + i];
    if (s >= NN || d >= NN) return;                       // never index from garbage
    int pos = atomicAdd(&bcur[w*B3 + (int)(d >> 3)], 1);
    if ((unsigned)pos < NE)                               // never store OOB
        binned[(size_t)w*NE + pos] = ((int)(d & 63) << 17) | (int)s;
}

// ---------------- matmul: out[r] = (in[r] * scale[r]) @ W (+ bias) ----------------
template<bool HAS_BIAS>
__global__ __launch_bounds__(256) void matmul_kernel(
        const float* __restrict__ in, float* __restrict__ out,
        const float* __restrict__ wmat, const float* __restrict__ scale,
        const float* __restrict__ bias) {
    __shared__ float wlds[NF*NF];     // 64 KB: full 128x128 weight
    __shared__ float alds[32*NF];     // 16 KB: 32 staged rows
    for (int i = threadIdx.x; i < NF*NF/4; i += 256)
        ((float4*)wlds)[i] = ((const float4*)wmat)[i];
    __syncthreads();

    int cg = threadIdx.x & 31;
    int rg = threadIdx.x >> 5;
    int rowbase = blockIdx.x * 128;

    for (int pass = 0; pass < 4; ++pass) {
        int r0 = rowbase + pass*32;
        for (int i = threadIdx.x; i < 32*NF/4; i += 256) {
            int row = i >> 5;
            float sc = scale[r0 + row];
            float4 v = ((const float4*)(in + (size_t)r0*NF))[i];
            v.x *= sc; v.y *= sc; v.z *= sc; v.w *= sc;
            ((float4*)alds)[i] = v;
        }
        __syncthreads();

        float4 acc0 = {0,0,0,0}, acc1 = {0,0,0,0}, acc2 = {0,0,0,0}, acc3 = {0,0,0,0};
        const float* a0 = alds + (rg*4+0)*NF;
        const float* a1 = alds + (rg*4+1)*NF;
        const float* a2 = alds + (rg*4+2)*NF;
        const float* a3 = alds + (rg*4+3)*NF;
        for (int k = 0; k < NF; ++k) {
            float4 wv = ((const float4*)(wlds + k*NF))[cg];
            float b0 = a0[k], b1 = a1[k], b2 = a2[k], b3 = a3[k];
            acc0.x += wv.x*b0; acc0.y += wv.y*b0; acc0.z += wv.z*b0; acc0.w += wv.w*b0;
            acc1.x += wv.x*b1; acc1.y += wv.y*b1; acc1.z += wv.z*b1; acc1.w += wv.w*b1;
            acc2.x += wv.x*b2; acc2.y += wv.y*b2; acc2.z += wv.z*b2; acc2.w += wv.w*b2;
            acc3.x += wv.x*b3; acc3.y += wv.y*b3; acc3.z += wv.z*b3; acc3.w += wv.w*b3;
        }
        if (HAS_BIAS) {
            float4 b = ((const float4*)bias)[cg];
            acc0.x += b.x; acc0.y += b.y; acc0.z += b.z; acc0.w += b.w;
            acc1.x += b.x; acc1.y += b.y; acc1.z += b.z; acc1.w += b.w;
            acc2.x += b.x; acc2.y += b.y; acc2.z += b.z; acc2.w += b.w;
            acc3.x += b.x; acc3.y += b.y; acc3.z += b.z; acc3.w += b.w;
        }
        ((float4*)(out + (size_t)(r0 + rg*4+0)*NF))[cg] = acc0;
        ((float4*)(out + (size_t)(r0 + rg*4+1)*NF))[cg] = acc1;
        ((float4*)(out + (size_t)(r0 + rg*4+2)*NF))[cg] = acc2;
        ((float4*)(out + (size_t)(r0 + rg*4+3)*NF))[cg] = acc3;
        __syncthreads();
    }
}

// ---------------- fused LDS counting-sort + register gather ----------------
__global__ __launch_bounds__(256) void sortgather_kernel(
        const float* __restrict__ P, const float* __restrict__ inv_in,
        const int* __restrict__ row_start, const int* __restrict__ binned,
        const float* __restrict__ bias, float* __restrict__ out) {
    __shared__ int ecnt[GC];
    __shared__ int eoff[GC];
    __shared__ int ecur[GC];
    __shared__ int elraw[CAP];
    __shared__ int elist[CAP];

    int w = blockIdx.y, g = blockIdx.x;
    int tid  = threadIdx.x;
    int wave = tid >> 6;              // 0..3
    int half = (tid >> 5) & 1;
    int c    = tid & 31;

    int n0  = g << 6;
    int beg = row_start[w*NN + n0];
    int end = (g == NG-1) ? NE : row_start[w*NN + n0 + GC];

    const int* bb = binned + (size_t)w*NE;
    const float4* p4 = (const float4*)P;
    size_t wbase = (size_t)w*NN;

    float4 acc[16];
    #pragma unroll
    for (int n = 0; n < 16; ++n) acc[n] = make_float4(0.f,0.f,0.f,0.f);

    for (int cb = beg; cb < end; cb += CAP) {
        int m = end - cb; if (m > CAP) m = CAP;
        if (tid < GC) ecnt[tid] = 0;
        __syncthreads();
        for (int i = tid; i < m; i += 256) {
            int pk = bb[cb + i];
            elraw[i] = pk;
            atomicAdd(&ecnt[(pk >> 17) & 63], 1);
        }
        __syncthreads();
        if (tid < 64) {
            int v = ecnt[tid];
            int x = v;
            #pragma unroll
            for (int o = 1; o < 64; o <<= 1) {
                int t = __shfl_up(x, o);
                if (tid >= o) x += t;
            }
            eoff[tid] = x - v;
            ecur[tid] = x - v;
        }
        __syncthreads();
        for (int i = tid; i < m; i += 256) {
            int pk = elraw[i];
            int dl = (pk >> 17) & 63;
            int pos = atomicAdd(&ecur[dl], 1);
            int s = pk & 0x1FFFF;
            elist[pos] = (s < NN) ? s : (NN-1);
        }
        __syncthreads();
        #pragma unroll
        for (int n = 0; n < 16; ++n) {
            int nl  = wave*16 + n;
            int off = eoff[nl];
            int fin = off + ecnt[nl];
            int e = off;
            for (; e + 3 < fin; e += 4) {
                int s0 = elist[e + half*2];
                int s1 = elist[e + half*2 + 1];
                float4 v0 = p4[(wbase + s0)*32 + c];
                float4 v1 = p4[(wbase + s1)*32 + c];
                acc[n].x += v0.x + v1.x; acc[n].y += v0.y + v1.y;
                acc[n].z += v0.z + v1.z; acc[n].w += v0.w + v1.w;
            }
            for (; e < fin; e += 2) {
                int ee = e + half;
                if (ee < fin) {
                    int s = elist[ee];
                    float4 v = p4[(wbase + s)*32 + c];
                    acc[n].x += v.x; acc[n].y += v.y;
                    acc[n].z += v.z; acc[n].w += v.w;
                }
            }
        }
        __syncthreads();
    }

    float4 bv = ((const float4*)bias)[c];
    #pragma unroll
    for (int n = 0; n < 16; ++n) {
        float4 a = acc[n];
        a.x += __shfl_down(a.x, 32);
        a.y += __shfl_down(a.y, 32);
        a.z += __shfl_down(a.z, 32);
        a.w += __shfl_down(a.w, 32);
        if (half == 0) {
            int node = n0 + wave*16 + n;
            if (node < NN) {
                float sc = inv_in[w*NN + node];
                float4 o;
                o.x = a.x*sc + bv.x; o.y = a.y*sc + bv.y;
                o.z = a.z*sc + bv.z; o.w = a.w*sc + bv.w;
                ((float4*)out)[(wbase + node)*32 + c] = o;
            }
        }
    }
}

// ---------------- fallback path (ws too small for P): per-node CSR + float2 gather ----------------
__global__ void cursor_copy_kernel(const int* __restrict__ row_start, int* __restrict__ cursor) {
    int i = blockIdx.x * blockDim.x + threadIdx.x;
    if (i < WN) cursor[i] = row_start[i];
}

__global__ void place_kernel(const int* __restrict__ src, const int* __restrict__ dst,
                             int* __restrict__ cursor, int* __restrict__ sorted) {
    int w = blockIdx.y;
    int i = blockIdx.x * blockDim.x + threadIdx.x;
    if (i >= NE) return;
    unsigned s = (unsigned)src[(size_t)w*NE + i];
    unsigned d = (unsigned)dst[(size_t)w*NE + i];
    if (s >= NN || d >= NN) return;
    int pos = atomicAdd(&cursor[w*NN + (int)d], 1);
    if ((unsigned)pos < NE)
        sorted[(size_t)w*NE + pos] = (int)s;
}

__global__ __launch_bounds__(256) void gather_fallback_kernel(
        const float* __restrict__ feats, const float* __restrict__ inv_out,
        const int* __restrict__ row_start, const int* __restrict__ deg_in,
        const int* __restrict__ sorted, float* __restrict__ agg) {
    int g    = blockIdx.x * 4 + (threadIdx.x >> 6);
    int lane = threadIdx.x & 63;
    int w    = g / NN;
    int beg  = row_start[g];
    int end  = beg + deg_in[g];
    const int*    ss = sorted + (size_t)w*NE;
    const float2* f2 = (const float2*)feats;
    float ax = 0.f, ay = 0.f;
    for (int e = beg; e < end; ++e) {
        int s = ss[e];
        float sc = inv_out[w*NN + s];
        float2 v = f2[((size_t)(w*NN + s))*64 + lane];
        ax += v.x * sc;
        ay += v.y * sc;
    }
    ((float2*)agg)[(size_t)g*64 + lane] = make_float2(ax, ay);
}

extern "C" void kernel_launch(void* const* d_in, const int* in_sizes, int n_in,
                              void* d_out, int out_size, void* d_ws, size_t ws_size,
                              hipStream_t stream) {
    const float* feats = (const float*)d_in[0];
    const float* wmat  = (const float*)d_in[1];
    const float* bias  = (const float*)d_in[2];
    const int*   src   = (const int*)d_in[3];
    const int*   dst   = (const int*)d_in[4];
    float* out = (float*)d_out;

    // workspace layout (ints unless noted):
    //   cnt_out[WN] cnt_in[WN] row_start[WN] cursor/bcur[WN]
    //   inv_out(f32)[WN] inv_in(f32)[WN] partials[1024] binned/sorted[WK*NE]
    //   P(f32)[WN*NF]  (P region doubles as hist partials before matmul)
    int* ws        = (int*)d_ws;
    int* cnt_out   = ws;
    int* cnt_in    = ws + WN;
    int* row_start = ws + 2*WN;
    int* cursor    = ws + 3*WN;                 // fast path: bcur (WK*B3 = 50000 ints)
    int* bcur      = cursor;
    float* inv_out = (float*)(ws + 4*WN);
    float* inv_in  = (float*)(ws + 5*WN);
    int* partials  = ws + 6*WN;                 // W*TPW ints, padded to 1024
    int* binned    = ws + 6*WN + 1024;          // W*NE ints (aka sorted in fallback)
    float* P       = (float*)(binned + (size_t)WK*NE);  // WN*NF floats
    int* hpart     = (int*)P;                   // WK*2*NSEG*NN ints = 25.6 MB << P region

    size_t csr_bytes = ((size_t)6*WN + 1024 + (size_t)WK*NE) * sizeof(int);
    size_t p_bytes   = (size_t)WN * NF * sizeof(float);
    bool use_csr = ws_size >= csr_bytes;
    bool use_p   = ws_size >= csr_bytes + p_bytes;

    if (use_csr && use_p) {
        // -------- fast path: zero global atomics for degree counting --------
        hist_kernel<<<dim3(NSEG*NRANGE, WK, 2), 256, 0, stream>>>(src, dst, hpart);
        reduce_kernel<<<(2*WN+255)/256, 256, 0, stream>>>(hpart, cnt_out, cnt_in);
        scan1_kernel<<<dim3(TPW, WK), TILE, 0, stream>>>(cnt_in, row_start, partials);
        scan2_kernel<<<WK, 256, 0, stream>>>(partials);
        scan3_kernel<<<dim3(TPW, WK), TILE, 0, stream>>>(row_start, partials);
        finalize_kernel<<<(WN+255)/256, 256, 0, stream>>>(cnt_out, cnt_in, inv_out, inv_in);
        bucket_init_kernel<<<(WK*B3+255)/256, 256, 0, stream>>>(row_start, bcur);
        bin_kernel<<<dim3(NE/256, WK), 256, 0, stream>>>(src, dst, bcur, binned);
        // P = diag(inv_out) X W   (projection before aggregation; overwrites hpart)
        matmul_kernel<false><<<WN/128, 256, 0, stream>>>(
            feats, P, wmat, inv_out, nullptr);
        sortgather_kernel<<<dim3(NG, WK), 256, 0, stream>>>(
            P, inv_in, row_start, binned, bias, out);
    } else if (use_csr) {
        hipMemsetAsync(cnt_out, 0, (size_t)2*WN*sizeof(int), stream);
        deg_kernel<<<dim3(NE/256, WK), 256, 0, stream>>>(src, dst, cnt_out, cnt_in);
        scan1_kernel<<<dim3(TPW, WK), TILE, 0, stream>>>(cnt_in, row_start, partials);
        scan2_kernel<<<WK, 256, 0, stream>>>(partials);
        scan3_kernel<<<dim3(TPW, WK), TILE, 0, stream>>>(row_start, partials);
        finalize_kernel<<<(WN+255)/256, 256, 0, stream>>>(cnt_out, cnt_in, inv_out, inv_in);
        cursor_copy_kernel<<<(WN+255)/256, 256, 0, stream>>>(row_start, cursor);
        place_kernel<<<dim3(NE/256, WK), 256, 0, stream>>>(src, dst, cursor, binned);
        gather_fallback_kernel<<<WN/4, 256, 0, stream>>>(
            feats, inv_out, row_start, cnt_in, binned, out);
        matmul_kernel<true><<<WN/128, 256, 0, stream>>>(
            out, out, wmat, inv_in, bias);
    } else {
        // emergency: shouldn't happen (ws known >= csr from round 1)
        hipMemsetAsync(cnt_out, 0, (size_t)2*WN*sizeof(int), stream);
        deg_kernel<<<dim3(NE/256, WK), 256, 0, stream>>>(src, dst, cnt_out, cnt_in);
        finalize_kernel<<<(WN+255)/256, 256, 0, stream>>>(cnt_out, cnt_in, inv_out, inv_in);
        hipMemsetAsync(out, 0, (size_t)WN*NF*sizeof(float), stream);
        matmul_kernel<true><<<WN/128, 256, 0, stream>>>(
            out, out, wmat, inv_in, bias);
    }
}